// Round 6
// baseline (8570.727 us; speedup 1.0000x reference)
//
#include <hip/hip_runtime.h>
#include <hip/hip_bf16.h>

#define DEVI __device__ __forceinline__

typedef short  bf16x8 __attribute__((ext_vector_type(8)));
typedef float  f32x4  __attribute__((ext_vector_type(4)));

static constexpr int BB   = 16;
static constexpr int MM   = 4;
static constexpr int CC   = 3;
static constexpr int IMG  = 224;
static constexpr int PPP  = 16;
static constexpr int DD   = 768;
static constexpr int LL   = 12;
static constexpr int HH   = 12;
static constexpr int DFF  = 3072;
static constexpr int NCLS = 1000;
static constexpr int GG   = 14;
static constexpr int SS   = 197;        // G*G+1
static constexpr int HD   = 64;
static constexpr int BT   = BB*SS;      // 3152 primal rows
static constexpr int BMT  = BB*MM*SS;   // 12608 tangent rows
static constexpr int RT   = BT+BMT;     // 15760 total rows
static constexpr int RP   = 15872;      // 62*256 padded rows
static constexpr int SP   = 208;        // padded seq (13*16)
static constexpr int QLD  = 3*DD;       // 2304
static constexpr int PRP  = BB*GG*GG;   // 3136 primal patch rows
static constexpr int PRT  = (BB+BB*MM)*GG*GG; // 15680 patch rows
static constexpr float EPSV  = 1e-6f;
static constexpr float SCALE = 0.125f;

// per-layer weight slab element counts
static constexpr int NQW  = QLD*DD;       // 1769472
static constexpr int NPW  = DD*DD;        // 589824
static constexpr int NF1W = DFF*DD;       // 2359296
static constexpr int NF2W = DD*DFF;       // 2359296
static constexpr int WTOT = NQW+NPW+NF1W+NF2W; // 7077888

DEVI unsigned short f2bf(float x){
  union { float f; unsigned u; } v; v.f = x;
  unsigned r = v.u + 0x7fffu + ((v.u>>16)&1u);
  return (unsigned short)(r>>16);
}
DEVI float bf2f(unsigned short x){
  union { unsigned u; float f; } v; v.u = ((unsigned)x)<<16;
  return v.f;
}
DEVI f32x4 mfma16(bf16x8 a, bf16x8 b, f32x4 c){
  return __builtin_amdgcn_mfma_f32_16x16x32_bf16(a,b,c,0,0,0);
}
typedef const void __attribute__((address_space(1)))* gas1;
typedef void __attribute__((address_space(3)))* las3;

// ---------------- conversions (vectorized: 8 elems/thread) ----------------

DEVI bf16x8 cvt8(const float* src){
  float4 a = *(const float4*)src;
  float4 b = *(const float4*)(src+4);
  bf16x8 o;
  o[0]=(short)f2bf(a.x); o[1]=(short)f2bf(a.y); o[2]=(short)f2bf(a.z); o[3]=(short)f2bf(a.w);
  o[4]=(short)f2bf(b.x); o[5]=(short)f2bf(b.y); o[6]=(short)f2bf(b.z); o[7]=(short)f2bf(b.w);
  return o;
}

__global__ __launch_bounds__(256) void f2bf8_kernel(const float* __restrict__ in,
    unsigned short* __restrict__ out, size_t n8){
  size_t i = (size_t)blockIdx.x*256 + threadIdx.x;
  if (i < n8) *(bf16x8*)(out + i*8) = cvt8(in + i*8);
}

// all 12 layers at once (grid (WTOT/8/256, 12))
__global__ __launch_bounds__(256) void conv_all_v(const float* __restrict__ qkvw,
    const float* __restrict__ projw, const float* __restrict__ f1w,
    const float* __restrict__ f2w, unsigned short* __restrict__ wl){
  int l = blockIdx.y;
  size_t i = ((size_t)blockIdx.x*256 + threadIdx.x)*8;
  const float* src;
  if (i < NQW)                src = qkvw + (size_t)l*NQW + i;
  else if (i < NQW+NPW)       src = projw + (size_t)l*NPW + (i-NQW);
  else if (i < NQW+NPW+NF1W)  src = f1w + (size_t)l*NF1W + (i-NQW-NPW);
  else                        src = f2w + (size_t)l*NF2W + (i-NQW-NPW-NF1W);
  *(bf16x8*)(wl + (size_t)l*WTOT + i) = cvt8(src);
}

// one layer (grid WTOT/8/256)
__global__ __launch_bounds__(256) void conv_layer_v(const float* __restrict__ qkvw,
    const float* __restrict__ projw, const float* __restrict__ f1w,
    const float* __restrict__ f2w, unsigned short* __restrict__ wl){
  size_t i = ((size_t)blockIdx.x*256 + threadIdx.x)*8;
  const float* src;
  if (i < NQW)                src = qkvw + i;
  else if (i < NQW+NPW)       src = projw + (i-NQW);
  else if (i < NQW+NPW+NF1W)  src = f1w + (i-NQW-NPW);
  else                        src = f2w + (i-NQW-NPW-NF1W);
  *(bf16x8*)(wl + i) = cvt8(src);
}

__global__ __launch_bounds__(256) void init_h(float* __restrict__ hh,
    const float* __restrict__ cls, const float* __restrict__ pos,
    const float* __restrict__ patch_b){
  size_t i = (size_t)blockIdx.x*256 + threadIdx.x;   // exact grid RP*DD/256
  int r = (int)(i/DD), c = (int)(i%DD);
  float v = 0.f;
  if (r < BT){
    int s_ = r % SS;
    v = pos[(size_t)s_*DD + c] + (s_==0 ? cls[c] : patch_b[c]);
  }
  hh[i] = v;
}

__global__ __launch_bounds__(256) void patchify_k(const float* __restrict__ x,
    const float* __restrict__ xt, unsigned short* __restrict__ pat){
  size_t i = (size_t)blockIdx.x*256 + threadIdx.x;   // exact grid PRT*DD/256
  int r = (int)(i/DD), kk = (int)(i%DD);
  int c = kk>>8, rem = kk&255, py = rem>>4, px = rem&15;
  const float* src;
  if (r < PRP){
    int b_ = r/(GG*GG), p = r%(GG*GG);
    src = x + (((size_t)b_*CC + c)*IMG + (size_t)(p/GG)*PPP + py)*IMG + (p%GG)*PPP + px;
  } else {
    int rr = r-PRP; int bm = rr/(GG*GG), p = rr%(GG*GG);
    src = xt + (((size_t)bm*CC + c)*IMG + (size_t)(p/GG)*PPP + py)*IMG + (p%GG)*PPP + px;
  }
  pat[i] = f2bf(*src);
}

// ---------------- LayerNorm JVP (grouped: primal + 4 tangents per block) ----------------

DEVI void blockSum4(float&a,float&b,float&c,float&d,float* red){
  #pragma unroll
  for (int off=32; off; off>>=1){
    a += __shfl_xor(a,off,64); b += __shfl_xor(b,off,64);
    c += __shfl_xor(c,off,64); d += __shfl_xor(d,off,64);
  }
  int w = threadIdx.x>>6;
  if ((threadIdx.x&63)==0){ red[w]=a; red[4+w]=b; red[8+w]=c; red[12+w]=d; }
  __syncthreads();
  a = red[0]+red[1]+red[2]+red[3];
  b = red[4]+red[5]+red[6]+red[7];
  c = red[8]+red[9]+red[10]+red[11];
  d = red[12]+red[13]+red[14]+red[15];
  __syncthreads();
}

// grid BT: block r handles primal row r=b*SS+s and tangent rows (b*MM+m)*SS+s
__global__ __launch_bounds__(256) void ln_group(const float* __restrict__ hh,
    const float* __restrict__ g, const float* __restrict__ bb,
    unsigned short* __restrict__ ybf){
  __shared__ float red[4][10];
  int r = blockIdx.x;
  int b_ = r/SS, s_ = r%SS;
  int t = threadIdx.x;
  const float* xx = hh + (size_t)r*DD;
  float x0=xx[t], x1=xx[t+256], x2=xx[t+512];
  size_t trow[4];
  float tv[4][3];
  #pragma unroll
  for (int m=0;m<4;m++){
    trow[m] = (size_t)BT + ((size_t)(b_*MM+m))*SS + s_;
    const float* tt = hh + trow[m]*DD;
    tv[m][0]=tt[t]; tv[m][1]=tt[t+256]; tv[m][2]=tt[t+512];
  }
  float s[10];
  s[0]=x0+x1+x2; s[1]=x0*x0+x1*x1+x2*x2;
  #pragma unroll
  for (int m=0;m<4;m++){
    s[2+2*m]=tv[m][0]+tv[m][1]+tv[m][2];
    s[3+2*m]=x0*tv[m][0]+x1*tv[m][1]+x2*tv[m][2];
  }
  #pragma unroll
  for (int k=0;k<10;k++){
    float v = s[k];
    #pragma unroll
    for (int off=32; off; off>>=1) v += __shfl_xor(v, off, 64);
    s[k] = v;
  }
  int w = t>>6;
  if ((t&63)==0){
    #pragma unroll
    for (int k=0;k<10;k++) red[w][k]=s[k];
  }
  __syncthreads();
  #pragma unroll
  for (int k=0;k<10;k++) s[k] = red[0][k]+red[1][k]+red[2][k]+red[3][k];
  float mu  = s[0]*(1.f/DD);
  float inv = rsqrtf(s[1]*(1.f/DD) - mu*mu + EPSV);
  float g0=g[t], g1=g[t+256], g2=g[t+512];
  float h0=(x0-mu)*inv, h1=(x1-mu)*inv, h2=(x2-mu)*inv;
  {
    unsigned short* y = ybf + (size_t)r*DD;
    y[t]     = f2bf(h0*g0 + bb[t]);
    y[t+256] = f2bf(h1*g1 + bb[t+256]);
    y[t+512] = f2bf(h2*g2 + bb[t+512]);
  }
  #pragma unroll
  for (int m=0;m<4;m++){
    float tmean = s[2+2*m]*(1.f/DD);
    float dot   = inv*(s[3+2*m]*(1.f/DD) - mu*tmean);
    unsigned short* y = ybf + trow[m]*DD;
    y[t]     = f2bf(g0*inv*(tv[m][0] - tmean - h0*dot));
    y[t+256] = f2bf(g1*inv*(tv[m][1] - tmean - h1*dot));
    y[t+512] = f2bf(g2*inv*(tv[m][2] - tmean - h2*dot));
  }
}

// final LN only for the 80 CLS rows the head consumes (grid BB + BB*MM)
__global__ __launch_bounds__(256) void ln_head(const float* __restrict__ hh,
    const float* __restrict__ g, const float* __restrict__ bb,
    unsigned short* __restrict__ ybf){
  __shared__ float red[16];
  int ri = blockIdx.x;
  int t = threadIdx.x;
  if (ri < BB){
    size_t row = (size_t)ri*SS;
    const float* x = hh + row*DD;
    float x0=x[t], x1=x[t+256], x2=x[t+512];
    float s1=x0+x1+x2, s2=x0*x0+x1*x1+x2*x2, s3=0.f, s4=0.f;
    blockSum4(s1,s2,s3,s4,red);
    float mu  = s1*(1.f/DD);
    float inv = rsqrtf(s2*(1.f/DD) - mu*mu + EPSV);
    unsigned short* y = ybf + row*DD;
    y[t]     = f2bf((x0-mu)*inv*g[t]     + bb[t]);
    y[t+256] = f2bf((x1-mu)*inv*g[t+256] + bb[t+256]);
    y[t+512] = f2bf((x2-mu)*inv*g[t+512] + bb[t+512]);
  } else {
    int t2 = ri - BB;                       // b*MM+m
    size_t row = (size_t)BT + (size_t)t2*SS;
    size_t prow = (size_t)(t2/MM)*SS;
    const float* tt = hh + row*DD;
    const float* xx = hh + prow*DD;
    float t0=tt[t], t1=tt[t+256], t2v=tt[t+512];
    float x0=xx[t], x1=xx[t+256], x2=xx[t+512];
    float s1=x0+x1+x2, s2=x0*x0+x1*x1+x2*x2;
    float s3=t0+t1+t2v, s4=x0*t0+x1*t1+x2*t2v;
    blockSum4(s1,s2,s3,s4,red);
    float mu  = s1*(1.f/DD);
    float inv = rsqrtf(s2*(1.f/DD) - mu*mu + EPSV);
    float tmean = s3*(1.f/DD);
    float dot   = inv*(s4*(1.f/DD) - mu*tmean);
    unsigned short* y = ybf + row*DD;
    y[t]     = f2bf(g[t]    *inv*(t0  - tmean - (x0-mu)*inv*dot));
    y[t+256] = f2bf(g[t+256]*inv*(t1  - tmean - (x1-mu)*inv*dot));
    y[t+512] = f2bf(g[t+512]*inv*(t2v - tmean - (x2-mu)*inv*dot));
  }
}

// ---------------- main GEMM: C = A(bf16,[rows][K]) * W(bf16,[N][K])^T ----------------
// 256x128 tile, 512 threads / 8 waves (4M x 2N), single-buffer 2-barrier schedule.
// rows < asplit read from Aalt instead of A (same lda).
// MODE 0: bf16 out, +bias for r<bias_limit (qkv, fc1)
// MODE 1: fp32 +=, +bias for r<bias_limit, guard r<Mrows (proj, fc2)
// MODE 2: fp32 += with patch row remap, guard r<PRT (patch embed)

template<int MODE>
__global__ __launch_bounds__(512,4) void gemm_bt(
    const unsigned short* __restrict__ A,
    const unsigned short* __restrict__ Aalt, int asplit, int lda,
    const unsigned short* __restrict__ W, int K, int N, int Mrows,
    float* __restrict__ outf, unsigned short* __restrict__ outb, int ldc,
    const float* __restrict__ bias, int bias_limit)
{
  __shared__ __attribute__((aligned(16))) unsigned short As[256*64];  // 32 KB
  __shared__ __attribute__((aligned(16))) unsigned short Bs[128*64];  // 16 KB
  const int tid = threadIdx.x;
  const int wave = tid>>6, lane = tid&63;
  const int tM = blockIdx.y, tN = blockIdx.x;
  f32x4 acc[4][4];
  f32x4 zf = {0.f,0.f,0.f,0.f};
  #pragma unroll
  for (int m=0;m<4;m++)
    #pragma unroll
    for (int n=0;n<4;n++) acc[m][n] = zf;
  const int wm = wave>>1, wn = wave&1;          // 4M x 2N waves
  const int lrow = lane&15, lk8 = (lane>>4)<<3;
  const int srow = tid>>3;            // 0..63
  const int scol = (tid&7)<<3;        // 0..56
  const int arow0 = tM*256;
  const int brow0 = tN*128;

  for (int k0=0; k0<K; k0+=64){
    #pragma unroll
    for (int i=0;i<4;i++){
      int row = arow0 + srow + i*64;
      const unsigned short* abase = (row < asplit) ? Aalt : A;
      const unsigned short* ga = abase + (size_t)row*lda + (k0+scol);
      __builtin_amdgcn_global_load_lds((gas1)ga, (las3)(As + i*4096 + wave*512), 16, 0, 0);
    }
    #pragma unroll
    for (int j=0;j<2;j++){
      const unsigned short* gb = W + (size_t)(brow0 + srow + j*64)*K + (k0+scol);
      __builtin_amdgcn_global_load_lds((gas1)gb, (las3)(Bs + j*4096 + wave*512), 16, 0, 0);
    }
    __syncthreads();
    #pragma unroll
    for (int kk=0; kk<64; kk+=32){
      bf16x8 af[4], bw[4];
      #pragma unroll
      for (int m=0;m<4;m++) af[m] = *(const bf16x8*)(As + (wm*64+m*16+lrow)*64 + kk+lk8);
      #pragma unroll
      for (int n=0;n<4;n++) bw[n] = *(const bf16x8*)(Bs + (wn*64+n*16+lrow)*64 + kk+lk8);
      #pragma unroll
      for (int m=0;m<4;m++)
        #pragma unroll
        for (int n=0;n<4;n++)
          acc[m][n] = mfma16(af[m], bw[n], acc[m][n]);
    }
    __syncthreads();
  }

  const int colbase = tN*128 + wn*64 + lrow;
  const int rowbase = tM*256 + wm*64 + ((lane>>4)<<2);
  #pragma unroll
  for (int n=0;n<4;n++){
    int col = colbase + n*16;
    #pragma unroll
    for (int m=0;m<4;m++){
      #pragma unroll
      for (int i=0;i<4;i++){
        int r = rowbase + m*16 + i;
        float v = acc[m][n][i];
        if (MODE==0){
          if (r < bias_limit) v += bias[col];
          outb[(size_t)r*ldc + col] = f2bf(v);
        } else if (MODE==1){
          if (r < Mrows){
            if (r < bias_limit) v += bias[col];
            outf[(size_t)r*ldc + col] += v;
          }
        } else {
          if (r < PRT){
            int orow;
            if (r < PRP) orow = (r/196)*197 + 1 + r%196;
            else { int rr = r-PRP; orow = BT + (rr/196)*197 + 1 + rr%196; }
            outf[(size_t)orow*ldc + col] += v;
          }
        }
      }
    }
  }
}

// ---------------- attention ----------------
// transpose v / tv into [inst][d=64][k=208] bf16, zero-padded k>=SS
__global__ __launch_bounds__(256) void transpose_v(const unsigned short* __restrict__ qkv,
    unsigned short* __restrict__ vT, unsigned short* __restrict__ tvT){
  __shared__ unsigned short tile[SP*65];
  int inst = blockIdx.x;
  size_t rowbase; unsigned short* dst; int h;
  if (inst < BB*HH){ int b_=inst/HH; h=inst%HH; rowbase=(size_t)b_*SS; dst = vT + (size_t)inst*HD*SP; }
  else { int i2=inst-BB*HH; int bm=i2/HH; h=i2%HH; rowbase=(size_t)BT+(size_t)bm*SS; dst = tvT + (size_t)i2*HD*SP; }
  int coff = 2*DD + h*HD;
  for (int i=threadIdx.x; i<SP*HD; i+=256){
    int k = i>>6, d = i&63;
    unsigned short v = (k<SS) ? qkv[(rowbase+k)*QLD + coff + d] : (unsigned short)0;
    tile[k*65+d] = v;
  }
  __syncthreads();
  for (int i=threadIdx.x; i<HD*SP; i+=256){
    int d = i/SP, k = i%SP;
    dst[(size_t)d*SP + k] = tile[k*65+d];
  }
}

// primal scores + fused softmax -> abf (bf16 probs, masked cols = 0)
__global__ __launch_bounds__(256) void attn_s1(const unsigned short* __restrict__ qkv,
                                               unsigned short* __restrict__ abf){
  int qt = blockIdx.x, inst = blockIdx.y;      // inst = b*H+h
  int wave = threadIdx.x>>6, lane = threadIdx.x&63;
  int lrow = lane&15, lk = (lane>>4)<<3;
  int q0 = qt*64 + wave*16;
  f32x4 acc[13];
  f32x4 zf = {0.f,0.f,0.f,0.f};
  #pragma unroll
  for (int n=0;n<13;n++) acc[n]=zf;
  int h = inst % HH, b_ = inst / HH;
  size_t prow = (size_t)b_*SS;
  const unsigned short* Ab = qkv + (prow + q0 + lrow)*QLD + h*HD + lk;
  const unsigned short* Bb = qkv + prow*QLD + DD + h*HD + lk;
  #pragma unroll
  for (int kk=0; kk<HD; kk+=32){
    bf16x8 av = *(const bf16x8*)(Ab + kk);
    #pragma unroll
    for (int n=0;n<13;n++){
      bf16x8 bv = *(const bf16x8*)(Bb + (size_t)(n*16+lrow)*QLD + kk);
      acc[n] = mfma16(av, bv, acc[n]);
    }
  }
  int grp = lane>>4;
  unsigned short* obase = abf + (size_t)inst*SP*SP;
  bool okc12 = (lrow < 5);   // col 192+lrow < 197
  #pragma unroll
  for (int i=0;i<4;i++){
    int qr = q0 + grp*4 + i;
    float val[13], e[13];
    float mv = -1e30f;
    #pragma unroll
    for (int n=0;n<13;n++){
      val[n] = acc[n][i]*SCALE;
      if (n<12 || okc12) mv = fmaxf(mv, val[n]);
    }
    #pragma unroll
    for (int off=8; off; off>>=1) mv = fmaxf(mv, __shfl_xor(mv, off, 64));
    float s = 0.f;
    #pragma unroll
    for (int n=0;n<13;n++){
      e[n] = (n<12 || okc12) ? __expf(val[n]-mv) : 0.f;
      s += e[n];
    }
    #pragma unroll
    for (int off=8; off; off>>=1) s += __shfl_xor(s, off, 64);
    float inv = 1.f/s;
    if (qr < SS){
      unsigned short* orow = obase + (size_t)qr*SP;
      #pragma unroll
      for (int n=0;n<13;n++) orow[n*16+lrow] = f2bf(e[n]*inv);
    }
  }
}

// tangent scores + fused ta -> tabf chunk (bf16, masked cols = 0)
__global__ __launch_bounds__(256) void attn_s2(const unsigned short* __restrict__ qkv,
    const unsigned short* __restrict__ abf, unsigned short* __restrict__ tabf,
    int bmix0){
  int qt = blockIdx.x, il = blockIdx.y;        // il = local inst
  int wave = threadIdx.x>>6, lane = threadIdx.x&63;
  int lrow = lane&15, lk = (lane>>4)<<3;
  int q0 = qt*64 + wave*16;
  f32x4 acc[13];
  f32x4 zf = {0.f,0.f,0.f,0.f};
  #pragma unroll
  for (int n=0;n<13;n++) acc[n]=zf;
  int h = il % HH;
  int bmix = bmix0 + il / HH;
  int b_ = bmix / MM;
  int bh = b_*HH + h;
  size_t prow = (size_t)b_*SS;
  size_t trow = (size_t)BT + (size_t)bmix*SS;
  #pragma unroll
  for (int p=0;p<2;p++){
    size_t ar = (p==0) ? trow : prow;   // tq then q
    size_t br = (p==1) ? trow : prow;   // k  then tk
    const unsigned short* Ab = qkv + (ar + q0 + lrow)*QLD + h*HD + lk;
    const unsigned short* Bb = qkv + br*QLD + DD + h*HD + lk;
    #pragma unroll
    for (int kk=0; kk<HD; kk+=32){
      bf16x8 av = *(const bf16x8*)(Ab + kk);
      #pragma unroll
      for (int n=0;n<13;n++){
        bf16x8 bv = *(const bf16x8*)(Bb + (size_t)(n*16+lrow)*QLD + kk);
        acc[n] = mfma16(av, bv, acc[n]);
      }
    }
  }
  int grp = lane>>4;
  const unsigned short* abase = abf + (size_t)bh*SP*SP;
  unsigned short* tbase = tabf + (size_t)il*SP*SP;
  #pragma unroll
  for (int i=0;i<4;i++){
    int qr = q0 + grp*4 + i;
    int qc = (qr < SS) ? qr : (SS-1);
    const unsigned short* arow = abase + (size_t)qc*SP;
    float av[13], tv[13];
    float dot = 0.f;
    #pragma unroll
    for (int n=0;n<13;n++){
      tv[n] = acc[n][i]*SCALE;
      av[n] = bf2f(arow[n*16+lrow]);
      dot += av[n]*tv[n];
    }
    #pragma unroll
    for (int off=8; off; off>>=1) dot += __shfl_xor(dot, off, 64);
    if (qr < SS){
      unsigned short* trow_ = tbase + (size_t)qr*SP;
      #pragma unroll
      for (int n=0;n<13;n++) trow_[n*16+lrow] = f2bf(av[n]*(tv[n]-dot));
    }
  }
}

// NP=1: o = a v (inst=b*H+h); NP=2: to = ta v + a tv (il local, bmix0 chunk base)
template<int NP>
__global__ __launch_bounds__(256) void attn_pv(
    const unsigned short* __restrict__ abf, const unsigned short* __restrict__ tabf,
    const unsigned short* __restrict__ vT,  const unsigned short* __restrict__ tvT,
    unsigned short* __restrict__ obf, int bmix0){
  int qt = blockIdx.x, il = blockIdx.y;
  int wave = threadIdx.x>>6, lane = threadIdx.x&63;
  int lrow = lane&15, lk = (lane>>4)<<3;
  int q0 = qt*64 + wave*16;
  int h = il % HH;
  int bmix = (NP==1) ? (il/HH) : (bmix0 + il/HH);
  int b_ = (NP==1) ? bmix : bmix/MM;
  int bh = b_*HH + h;
  f32x4 acc[4];
  f32x4 zf = {0.f,0.f,0.f,0.f};
  #pragma unroll
  for (int n=0;n<4;n++) acc[n]=zf;
  int arow = q0 + lrow; if (arow > SP-1) arow = SP-1;
  #pragma unroll
  for (int p=0;p<NP;p++){
    const unsigned short* Ab = (NP==2 && p==0) ? tabf + (size_t)il*SP*SP
                                               : abf + (size_t)bh*SP*SP;
    const unsigned short* Bb = (NP==2 && p==1) ? tvT + (size_t)(bmix*HH+h)*HD*SP
                                               : vT + (size_t)bh*HD*SP;
    #pragma unroll
    for (int ks=0; ks<6; ks++){
      int kb = ks*32 + lk;                  // 0..168 ; covers k<192
      bf16x8 av = *(const bf16x8*)(Ab + (size_t)arow*SP + kb);
      #pragma unroll
      for (int n=0;n<4;n++){
        bf16x8 bv = *(const bf16x8*)(Bb + (size_t)(n*16+lrow)*SP + kb);
        acc[n] = mfma16(av, bv, acc[n]);
      }
    }
    { // tail k=192..207 (half-slice): lanes with lk<16 handle it, others add zero
      int kb = 192 + lk;
      const bf16x8 ZV = {0,0,0,0,0,0,0,0};
      bool ok = (lk < 16);
      bf16x8 av = ok ? *(const bf16x8*)(Ab + (size_t)arow*SP + kb) : ZV;
      #pragma unroll
      for (int n=0;n<4;n++){
        bf16x8 bv = ok ? *(const bf16x8*)(Bb + (size_t)(n*16+lrow)*SP + kb) : ZV;
        acc[n] = mfma16(av, bv, acc[n]);
      }
    }
  }
  size_t orow0 = (NP==1) ? (size_t)bmix*SS : (size_t)BT + (size_t)bmix*SS;
  int qr0 = q0 + ((lane>>4)<<2);
  #pragma unroll
  for (int n=0;n<4;n++){
    int cc = h*HD + n*16 + lrow;
    #pragma unroll
    for (int i=0;i<4;i++){
      int qr = qr0 + i;
      if (qr < SS) obf[(orow0+qr)*DD + cc] = f2bf(acc[n][i]);
    }
  }
}

// ---------------- GELU JVP (grouped: primal + 4 tangents per block) ----------------
// grid BT: primal row -> pgbf; 4 tangent rows updated in place (share cdf/pdf)
__global__ __launch_bounds__(256) void gelu_group(unsigned short* __restrict__ fc1o,
                                                  unsigned short* __restrict__ pgbf){
  int r = blockIdx.x;
  int b_ = r/SS, s_ = r%SS;
  const bf16x8* pb = (const bf16x8*)(fc1o + (size_t)r*DFF);
  bf16x8* pg = (bf16x8*)(pgbf + (size_t)r*DFF);
  bf16x8* tb[4];
  #pragma unroll
  for (int m=0;m<4;m++)
    tb[m] = (bf16x8*)(fc1o + ((size_t)BT + (size_t)(b_*MM+m)*SS + s_)*DFF);
  for (int c = threadIdx.x; c < DFF/8; c += 256){
    bf16x8 xv = pb[c];
    float deriv[8];
    bf16x8 o;
    #pragma unroll
    for (int j=0;j<8;j++){
      float x = bf2f((unsigned short)xv[j]);
      float cdf = 0.5f*(1.f + erff(x*0.70710678118654752f));
      float pdf = __expf(-0.5f*x*x)*0.39894228040143267f;
      o[j] = (short)f2bf(x*cdf);
      deriv[j] = cdf + x*pdf;
    }
    pg[c] = o;
    #pragma unroll
    for (int m=0;m<4;m++){
      bf16x8 tv8 = tb[m][c];
      bf16x8 w;
      #pragma unroll
      for (int j=0;j<8;j++) w[j] = (short)f2bf(bf2f((unsigned short)tv8[j])*deriv[j]);
      tb[m][c] = w;
    }
  }
}

// ---------------- head ----------------
__global__ __launch_bounds__(256) void head_k(const unsigned short* __restrict__ ybf,
    const float* __restrict__ hw, const float* __restrict__ hb, float* __restrict__ out){
  __shared__ float ysh[DD];
  int ri = blockIdx.x;
  size_t yrow; float* o; bool wb;
  if (ri < BB){ yrow = (size_t)ri*SS; o = out + (size_t)ri*NCLS; wb = true; }
  else { int t2 = ri-BB; yrow = (size_t)BT + (size_t)t2*SS; o = out + (size_t)BB*NCLS + (size_t)t2*NCLS; wb = false; }
  for (int d=threadIdx.x; d<DD; d+=256) ysh[d] = bf2f(ybf[yrow*DD + d]);
  __syncthreads();
  for (int n=threadIdx.x; n<NCLS; n+=256){
    const float* wrow = hw + (size_t)n*DD;
    float acc = wb ? hb[n] : 0.f;
    for (int d=0; d<DD; d++) acc += ysh[d]*wrow[d];
    o[n] = acc;
  }
}

// ---------------- launch ----------------
extern "C" void kernel_launch(void* const* d_in, const int* in_sizes, int n_in,
                              void* d_out, int out_size, void* d_ws, size_t ws_size,
                              hipStream_t stream)
{
  const float* x      = (const float*)d_in[0];
  const float* xt     = (const float*)d_in[1];
  const float* patch_w= (const float*)d_in[2];
  const float* patch_b= (const float*)d_in[3];
  const float* cls    = (const float*)d_in[4];
  const float* pos    = (const float*)d_in[5];
  const float* ln1_g  = (const float*)d_in[6];
  const float* ln1_b  = (const float*)d_in[7];
  const float* qkv_w  = (const float*)d_in[8];
  const float* qkv_b  = (const float*)d_in[9];
  const float* proj_w = (const float*)d_in[10];
  const float* proj_b = (const float*)d_in[11];
  const float* ln2_g  = (const float*)d_in[12];
  const float* ln2_b  = (const float*)d_in[13];
  const float* fc1_w  = (const float*)d_in[14];
  const float* fc1_b  = (const float*)d_in[15];
  const float* fc2_w  = (const float*)d_in[16];
  const float* fc2_b  = (const float*)d_in[17];
  const float* nf_g   = (const float*)d_in[18];
  const float* nf_b   = (const float*)d_in[19];
  const float* head_w = (const float*)d_in[20];
  const float* head_b = (const float*)d_in[21];
  float* out = (float*)d_out;

  char* ws = (char*)d_ws;
  size_t off = 0;
  auto alloc = [&](size_t bytes)->char*{
    char* p = ws + off;
    off = (off + bytes + 255) & ~(size_t)255;
    return p;
  };

  unsigned short *w_patch, *wl, *ybf, *qkvbf, *vT, *tvT, *abf, *tabf, *fc1o, *pgbf;
  float *hh;
  auto layout = [&](bool allw, int nbm)->size_t{
    off = 0;
    w_patch = (unsigned short*)alloc((size_t)DD*DD*2);
    wl      = (unsigned short*)alloc((size_t)WTOT*2*(allw?LL:1));
    hh      = (float*)alloc((size_t)RP*DD*4);
    ybf     = (unsigned short*)alloc((size_t)RP*DD*2);
    size_t slab0 = off;
    qkvbf = (unsigned short*)alloc((size_t)RP*QLD*2);
    vT    = (unsigned short*)alloc((size_t)BB*HH*HD*SP*2);
    tvT   = (unsigned short*)alloc((size_t)BB*MM*HH*HD*SP*2);
    abf   = (unsigned short*)alloc((size_t)BB*HH*SP*SP*2);
    tabf  = (unsigned short*)alloc((size_t)nbm*HH*SP*SP*2);
    size_t endA = off;
    off = slab0;
    fc1o = (unsigned short*)alloc((size_t)RP*DFF*2);
    pgbf = (unsigned short*)alloc((size_t)BT*DFF*2);
    size_t endB = off;
    return (endA > endB) ? endA : endB;
  };

  bool allw = true; int nbm = BB*MM;   // preferred: all weights + 1 chunk
  size_t need = layout(true, BB*MM);
  if (need > ws_size){ need = layout(true, BB*MM/4);  allw=true;  nbm=BB*MM/4; }
  if (need > ws_size){ need = layout(false, BB*MM);   allw=false; nbm=BB*MM;   }
  if (need > ws_size){ need = layout(false, BB*MM/4); allw=false; nbm=BB*MM/4; }
  if (need > ws_size){
    (void)hipMemsetAsync(d_out, 0x7f, (size_t)out_size*4, stream);   // loud sentinel
    return;
  }
  int nch = (BB*MM)/nbm;

  dim3 blk(256);
  dim3 gblk(512);
  f2bf8_kernel<<<dim3((DD*DD/8+255)/256), blk, 0, stream>>>(patch_w, w_patch, (size_t)DD*DD/8);
  if (allw)
    conv_all_v<<<dim3(WTOT/8/256, LL), blk, 0, stream>>>(qkv_w, proj_w, fc1_w, fc2_w, wl);
  init_h<<<dim3((RP*DD)/256), blk, 0, stream>>>(hh, cls, pos, patch_b);
  patchify_k<<<dim3((PRT*DD)/256), blk, 0, stream>>>(x, xt, ybf);
  gemm_bt<2><<<dim3(DD/128, RP/256), gblk, 0, stream>>>(ybf, nullptr, 0, DD, w_patch, DD, DD, PRT,
                                                        hh, nullptr, DD, nullptr, 0);

  for (int l=0; l<LL; l++){
    if (!allw)
      conv_layer_v<<<dim3(WTOT/8/256), blk, 0, stream>>>(qkv_w+(size_t)l*NQW, proj_w+(size_t)l*NPW,
                                                         fc1_w+(size_t)l*NF1W, fc2_w+(size_t)l*NF2W, wl);
    const unsigned short* w_qkv = wl + (allw ? (size_t)l*WTOT : 0);
    const unsigned short* w_proj= w_qkv + NQW;
    const unsigned short* w_fc1 = w_qkv + NQW + NPW;
    const unsigned short* w_fc2 = w_qkv + NQW + NPW + NF1W;

    ln_group<<<dim3(BT), blk, 0, stream>>>(hh, ln1_g+(size_t)l*DD, ln1_b+(size_t)l*DD, ybf);
    gemm_bt<0><<<dim3(QLD/128, RP/256), gblk, 0, stream>>>(ybf, nullptr, 0, DD, w_qkv,
        DD, QLD, RT, nullptr, qkvbf, QLD, qkv_b+(size_t)l*QLD, BT);
    transpose_v<<<dim3(BB*HH + BB*MM*HH), blk, 0, stream>>>(qkvbf, vT, tvT);
    attn_s1<<<dim3(4, BB*HH), blk, 0, stream>>>(qkvbf, abf);
    attn_pv<1><<<dim3(4, BB*HH), blk, 0, stream>>>(abf, nullptr, vT, nullptr, ybf, 0);
    for (int c=0; c<nch; c++){
      attn_s2<<<dim3(4, nbm*HH), blk, 0, stream>>>(qkvbf, abf, tabf, c*nbm);
      attn_pv<2><<<dim3(4, nbm*HH), blk, 0, stream>>>(abf, tabf, vT, tvT, ybf, c*nbm);
    }
    gemm_bt<1><<<dim3(DD/128, RP/256), gblk, 0, stream>>>(ybf, nullptr, 0, DD, w_proj,
        DD, DD, RT, hh, nullptr, DD, proj_b+(size_t)l*DD, BT);
    ln_group<<<dim3(BT), blk, 0, stream>>>(hh, ln2_g+(size_t)l*DD, ln2_b+(size_t)l*DD, ybf);
    gemm_bt<0><<<dim3(DFF/128, RP/256), gblk, 0, stream>>>(ybf, nullptr, 0, DD, w_fc1,
        DD, DFF, RT, nullptr, fc1o, DFF, fc1_b+(size_t)l*DFF, BT);
    gelu_group<<<dim3(BT), blk, 0, stream>>>(fc1o, pgbf);
    gemm_bt<1><<<dim3(DD/128, RP/256), gblk, 0, stream>>>(fc1o, pgbf, BT, DFF, w_fc2,
        DFF, DD, RT, hh, nullptr, DD, fc2_b+(size_t)l*DD, BT);
  }

  ln_head<<<dim3(BB + BB*MM), blk, 0, stream>>>(hh, nf_g, nf_b, ybf);
  head_k<<<dim3(BB + BB*MM), blk, 0, stream>>>(ybf, head_w, head_b, out);
}

// Round 7
// 7466.795 us; speedup vs baseline: 1.1478x; 1.1478x over previous
//
#include <hip/hip_runtime.h>
#include <hip/hip_bf16.h>

#define DEVI __device__ __forceinline__

typedef short  bf16x8 __attribute__((ext_vector_type(8)));
typedef float  f32x4  __attribute__((ext_vector_type(4)));

static constexpr int BB   = 16;
static constexpr int MM   = 4;
static constexpr int CC   = 3;
static constexpr int IMG  = 224;
static constexpr int PPP  = 16;
static constexpr int DD   = 768;
static constexpr int LL   = 12;
static constexpr int HH   = 12;
static constexpr int DFF  = 3072;
static constexpr int NCLS = 1000;
static constexpr int GG   = 14;
static constexpr int SS   = 197;        // G*G+1
static constexpr int HD   = 64;
static constexpr int BT   = BB*SS;      // 3152 primal rows
static constexpr int BMT  = BB*MM*SS;   // 12608 tangent rows
static constexpr int RT   = BT+BMT;     // 15760 total rows
static constexpr int RP   = 15872;      // 124*128 padded rows
static constexpr int SP   = 208;        // padded seq (13*16)
static constexpr int LDP  = 216;        // LDS row stride (u16), 432B = 16B-aligned
static constexpr int QLD  = 3*DD;       // 2304
static constexpr int PRP  = BB*GG*GG;   // 3136 primal patch rows
static constexpr int PRT  = (BB+BB*MM)*GG*GG; // 15680 patch rows
static constexpr float EPSV  = 1e-6f;
static constexpr float SCALE = 0.125f;

// per-layer weight slab element counts
static constexpr int NQW  = QLD*DD;       // 1769472
static constexpr int NPW  = DD*DD;        // 589824
static constexpr int NF1W = DFF*DD;       // 2359296
static constexpr int NF2W = DD*DFF;       // 2359296
static constexpr int WTOT = NQW+NPW+NF1W+NF2W; // 7077888

DEVI unsigned short f2bf(float x){
  union { float f; unsigned u; } v; v.f = x;
  unsigned r = v.u + 0x7fffu + ((v.u>>16)&1u);
  return (unsigned short)(r>>16);
}
DEVI float bf2f(unsigned short x){
  union { unsigned u; float f; } v; v.u = ((unsigned)x)<<16;
  return v.f;
}
DEVI f32x4 mfma16(bf16x8 a, bf16x8 b, f32x4 c){
  return __builtin_amdgcn_mfma_f32_16x16x32_bf16(a,b,c,0,0,0);
}
typedef const void __attribute__((address_space(1)))* gas1;
typedef void __attribute__((address_space(3)))* las3;

// ---------------- conversions (vectorized: 8 elems/thread) ----------------

DEVI bf16x8 cvt8(const float* src){
  float4 a = *(const float4*)src;
  float4 b = *(const float4*)(src+4);
  bf16x8 o;
  o[0]=(short)f2bf(a.x); o[1]=(short)f2bf(a.y); o[2]=(short)f2bf(a.z); o[3]=(short)f2bf(a.w);
  o[4]=(short)f2bf(b.x); o[5]=(short)f2bf(b.y); o[6]=(short)f2bf(b.z); o[7]=(short)f2bf(b.w);
  return o;
}

__global__ __launch_bounds__(256) void f2bf8_kernel(const float* __restrict__ in,
    unsigned short* __restrict__ out, size_t n8){
  size_t i = (size_t)blockIdx.x*256 + threadIdx.x;
  if (i < n8) *(bf16x8*)(out + i*8) = cvt8(in + i*8);
}

// all 12 layers at once (grid (WTOT/8/256, 12))
__global__ __launch_bounds__(256) void conv_all_v(const float* __restrict__ qkvw,
    const float* __restrict__ projw, const float* __restrict__ f1w,
    const float* __restrict__ f2w, unsigned short* __restrict__ wl){
  int l = blockIdx.y;
  size_t i = ((size_t)blockIdx.x*256 + threadIdx.x)*8;
  const float* src;
  if (i < NQW)                src = qkvw + (size_t)l*NQW + i;
  else if (i < NQW+NPW)       src = projw + (size_t)l*NPW + (i-NQW);
  else if (i < NQW+NPW+NF1W)  src = f1w + (size_t)l*NF1W + (i-NQW-NPW);
  else                        src = f2w + (size_t)l*NF2W + (i-NQW-NPW-NF1W);
  *(bf16x8*)(wl + (size_t)l*WTOT + i) = cvt8(src);
}

// one layer (grid WTOT/8/256)
__global__ __launch_bounds__(256) void conv_layer_v(const float* __restrict__ qkvw,
    const float* __restrict__ projw, const float* __restrict__ f1w,
    const float* __restrict__ f2w, unsigned short* __restrict__ wl){
  size_t i = ((size_t)blockIdx.x*256 + threadIdx.x)*8;
  const float* src;
  if (i < NQW)                src = qkvw + i;
  else if (i < NQW+NPW)       src = projw + (i-NQW);
  else if (i < NQW+NPW+NF1W)  src = f1w + (i-NQW-NPW);
  else                        src = f2w + (i-NQW-NPW-NF1W);
  *(bf16x8*)(wl + i) = cvt8(src);
}

__global__ __launch_bounds__(256) void init_h(float* __restrict__ hh,
    const float* __restrict__ cls, const float* __restrict__ pos,
    const float* __restrict__ patch_b){
  size_t i = (size_t)blockIdx.x*256 + threadIdx.x;   // exact grid RP*DD/256
  int r = (int)(i/DD), c = (int)(i%DD);
  float v = 0.f;
  if (r < BT){
    int s_ = r % SS;
    v = pos[(size_t)s_*DD + c] + (s_==0 ? cls[c] : patch_b[c]);
  }
  hh[i] = v;
}

__global__ __launch_bounds__(256) void patchify_k(const float* __restrict__ x,
    const float* __restrict__ xt, unsigned short* __restrict__ pat){
  size_t i = (size_t)blockIdx.x*256 + threadIdx.x;   // exact grid PRT*DD/256
  int r = (int)(i/DD), kk = (int)(i%DD);
  int c = kk>>8, rem = kk&255, py = rem>>4, px = rem&15;
  const float* src;
  if (r < PRP){
    int b_ = r/(GG*GG), p = r%(GG*GG);
    src = x + (((size_t)b_*CC + c)*IMG + (size_t)(p/GG)*PPP + py)*IMG + (p%GG)*PPP + px;
  } else {
    int rr = r-PRP; int bm = rr/(GG*GG), p = rr%(GG*GG);
    src = xt + (((size_t)bm*CC + c)*IMG + (size_t)(p/GG)*PPP + py)*IMG + (p%GG)*PPP + px;
  }
  pat[i] = f2bf(*src);
}

// ---------------- LayerNorm JVP (grouped: primal + 4 tangents per block) ----------------

DEVI void blockSum4(float&a,float&b,float&c,float&d,float* red){
  #pragma unroll
  for (int off=32; off; off>>=1){
    a += __shfl_xor(a,off,64); b += __shfl_xor(b,off,64);
    c += __shfl_xor(c,off,64); d += __shfl_xor(d,off,64);
  }
  int w = threadIdx.x>>6;
  if ((threadIdx.x&63)==0){ red[w]=a; red[4+w]=b; red[8+w]=c; red[12+w]=d; }
  __syncthreads();
  a = red[0]+red[1]+red[2]+red[3];
  b = red[4]+red[5]+red[6]+red[7];
  c = red[8]+red[9]+red[10]+red[11];
  d = red[12]+red[13]+red[14]+red[15];
  __syncthreads();
}

// grid BT: block r handles primal row r=b*SS+s and tangent rows (b*MM+m)*SS+s
__global__ __launch_bounds__(256) void ln_group(const float* __restrict__ hh,
    const float* __restrict__ g, const float* __restrict__ bb,
    unsigned short* __restrict__ ybf){
  __shared__ float red[4][10];
  int r = blockIdx.x;
  int b_ = r/SS, s_ = r%SS;
  int t = threadIdx.x;
  const float* xx = hh + (size_t)r*DD;
  float x0=xx[t], x1=xx[t+256], x2=xx[t+512];
  size_t trow[4];
  float tv[4][3];
  #pragma unroll
  for (int m=0;m<4;m++){
    trow[m] = (size_t)BT + ((size_t)(b_*MM+m))*SS + s_;
    const float* tt = hh + trow[m]*DD;
    tv[m][0]=tt[t]; tv[m][1]=tt[t+256]; tv[m][2]=tt[t+512];
  }
  float s[10];
  s[0]=x0+x1+x2; s[1]=x0*x0+x1*x1+x2*x2;
  #pragma unroll
  for (int m=0;m<4;m++){
    s[2+2*m]=tv[m][0]+tv[m][1]+tv[m][2];
    s[3+2*m]=x0*tv[m][0]+x1*tv[m][1]+x2*tv[m][2];
  }
  #pragma unroll
  for (int k=0;k<10;k++){
    float v = s[k];
    #pragma unroll
    for (int off=32; off; off>>=1) v += __shfl_xor(v, off, 64);
    s[k] = v;
  }
  int w = t>>6;
  if ((t&63)==0){
    #pragma unroll
    for (int k=0;k<10;k++) red[w][k]=s[k];
  }
  __syncthreads();
  #pragma unroll
  for (int k=0;k<10;k++) s[k] = red[0][k]+red[1][k]+red[2][k]+red[3][k];
  float mu  = s[0]*(1.f/DD);
  float inv = rsqrtf(s[1]*(1.f/DD) - mu*mu + EPSV);
  float g0=g[t], g1=g[t+256], g2=g[t+512];
  float h0=(x0-mu)*inv, h1=(x1-mu)*inv, h2=(x2-mu)*inv;
  {
    unsigned short* y = ybf + (size_t)r*DD;
    y[t]     = f2bf(h0*g0 + bb[t]);
    y[t+256] = f2bf(h1*g1 + bb[t+256]);
    y[t+512] = f2bf(h2*g2 + bb[t+512]);
  }
  #pragma unroll
  for (int m=0;m<4;m++){
    float tmean = s[2+2*m]*(1.f/DD);
    float dot   = inv*(s[3+2*m]*(1.f/DD) - mu*tmean);
    unsigned short* y = ybf + trow[m]*DD;
    y[t]     = f2bf(g0*inv*(tv[m][0] - tmean - h0*dot));
    y[t+256] = f2bf(g1*inv*(tv[m][1] - tmean - h1*dot));
    y[t+512] = f2bf(g2*inv*(tv[m][2] - tmean - h2*dot));
  }
}

// final LN only for the 80 CLS rows the head consumes (grid BB + BB*MM)
__global__ __launch_bounds__(256) void ln_head(const float* __restrict__ hh,
    const float* __restrict__ g, const float* __restrict__ bb,
    unsigned short* __restrict__ ybf){
  __shared__ float red[16];
  int ri = blockIdx.x;
  int t = threadIdx.x;
  if (ri < BB){
    size_t row = (size_t)ri*SS;
    const float* x = hh + row*DD;
    float x0=x[t], x1=x[t+256], x2=x[t+512];
    float s1=x0+x1+x2, s2=x0*x0+x1*x1+x2*x2, s3=0.f, s4=0.f;
    blockSum4(s1,s2,s3,s4,red);
    float mu  = s1*(1.f/DD);
    float inv = rsqrtf(s2*(1.f/DD) - mu*mu + EPSV);
    unsigned short* y = ybf + row*DD;
    y[t]     = f2bf((x0-mu)*inv*g[t]     + bb[t]);
    y[t+256] = f2bf((x1-mu)*inv*g[t+256] + bb[t+256]);
    y[t+512] = f2bf((x2-mu)*inv*g[t+512] + bb[t+512]);
  } else {
    int t2 = ri - BB;                       // b*MM+m
    size_t row = (size_t)BT + (size_t)t2*SS;
    size_t prow = (size_t)(t2/MM)*SS;
    const float* tt = hh + row*DD;
    const float* xx = hh + prow*DD;
    float t0=tt[t], t1=tt[t+256], t2v=tt[t+512];
    float x0=xx[t], x1=xx[t+256], x2=xx[t+512];
    float s1=x0+x1+x2, s2=x0*x0+x1*x1+x2*x2;
    float s3=t0+t1+t2v, s4=x0*t0+x1*t1+x2*t2v;
    blockSum4(s1,s2,s3,s4,red);
    float mu  = s1*(1.f/DD);
    float inv = rsqrtf(s2*(1.f/DD) - mu*mu + EPSV);
    float tmean = s3*(1.f/DD);
    float dot   = inv*(s4*(1.f/DD) - mu*tmean);
    unsigned short* y = ybf + row*DD;
    y[t]     = f2bf(g[t]    *inv*(t0  - tmean - (x0-mu)*inv*dot));
    y[t+256] = f2bf(g[t+256]*inv*(t1  - tmean - (x1-mu)*inv*dot));
    y[t+512] = f2bf(g[t+512]*inv*(t2v - tmean - (x2-mu)*inv*dot));
  }
}

// ---------------- main GEMM: C = A(bf16,[rows][K]) * W(bf16,[N][K])^T ----------------
// 128x128 tile (R4-proven). rows < asplit read from Aalt instead of A (same lda).
// MODE 0: bf16 out, +bias for r<bias_limit (qkv, fc1)
// MODE 1: fp32 +=, +bias for r<bias_limit, guard r<Mrows (proj, fc2)
// MODE 2: fp32 += with patch row remap, guard r<PRT (patch embed)

template<int MODE>
__global__ __launch_bounds__(256,2) void gemm_bt(
    const unsigned short* __restrict__ A,
    const unsigned short* __restrict__ Aalt, int asplit, int lda,
    const unsigned short* __restrict__ W, int K, int N, int Mrows,
    float* __restrict__ outf, unsigned short* __restrict__ outb, int ldc,
    const float* __restrict__ bias, int bias_limit)
{
  __shared__ __attribute__((aligned(16))) unsigned short As[128*64];
  __shared__ __attribute__((aligned(16))) unsigned short Bs[128*64];
  const int tid = threadIdx.x;
  const int wave = tid>>6, lane = tid&63;
  const int tM = blockIdx.y, tN = blockIdx.x;
  f32x4 acc[4][4];
  f32x4 zf = {0.f,0.f,0.f,0.f};
  #pragma unroll
  for (int m=0;m<4;m++)
    #pragma unroll
    for (int n=0;n<4;n++) acc[m][n] = zf;
  const int wm = wave>>1, wn = wave&1;
  const int lrow = lane&15, lk8 = (lane>>4)<<3;
  const int srow = tid>>3;            // 0..31
  const int scol = (tid&7)<<3;        // 0..56
  const size_t arow0 = (size_t)tM*128;
  const size_t brow0 = (size_t)tN*128;

  for (int k0=0; k0<K; k0+=64){
    #pragma unroll
    for (int i=0;i<4;i++){
      int row = (int)arow0 + srow + i*32;
      const unsigned short* abase = (row < asplit) ? Aalt : A;
      const unsigned short* ga = abase + (size_t)row*lda + (k0+scol);
      __builtin_amdgcn_global_load_lds((gas1)ga, (las3)(As + i*2048 + wave*512), 16, 0, 0);
      const unsigned short* gb = W + (brow0+srow+i*32)*(size_t)K + (k0+scol);
      __builtin_amdgcn_global_load_lds((gas1)gb, (las3)(Bs + i*2048 + wave*512), 16, 0, 0);
    }
    __syncthreads();
    #pragma unroll
    for (int kk=0; kk<64; kk+=32){
      bf16x8 af[4], bw[4];
      #pragma unroll
      for (int m=0;m<4;m++) af[m] = *(const bf16x8*)(As + (wm*64+m*16+lrow)*64 + kk+lk8);
      #pragma unroll
      for (int n=0;n<4;n++) bw[n] = *(const bf16x8*)(Bs + (wn*64+n*16+lrow)*64 + kk+lk8);
      #pragma unroll
      for (int m=0;m<4;m++)
        #pragma unroll
        for (int n=0;n<4;n++)
          acc[m][n] = mfma16(af[m], bw[n], acc[m][n]);
    }
    __syncthreads();
  }

  const int colbase = tN*128 + wn*64 + lrow;
  const int rowbase = tM*128 + wm*64 + ((lane>>4)<<2);
  #pragma unroll
  for (int n=0;n<4;n++){
    int col = colbase + n*16;
    #pragma unroll
    for (int m=0;m<4;m++){
      #pragma unroll
      for (int i=0;i<4;i++){
        int r = rowbase + m*16 + i;
        float v = acc[m][n][i];
        if (MODE==0){
          if (r < bias_limit) v += bias[col];
          outb[(size_t)r*ldc + col] = f2bf(v);
        } else if (MODE==1){
          if (r < Mrows){
            if (r < bias_limit) v += bias[col];
            outf[(size_t)r*ldc + col] += v;
          }
        } else {
          if (r < PRT){
            int orow;
            if (r < PRP) orow = (r/196)*197 + 1 + r%196;
            else { int rr = r-PRP; orow = BT + (rr/196)*197 + 1 + rr%196; }
            outf[(size_t)orow*ldc + col] += v;
          }
        }
      }
    }
  }
}

// ---------------- attention ----------------
// transpose v / tv into [inst][d=64][k=208] bf16, zero-padded k>=SS
__global__ __launch_bounds__(256) void transpose_v(const unsigned short* __restrict__ qkv,
    unsigned short* __restrict__ vT, unsigned short* __restrict__ tvT){
  __shared__ unsigned short tile[SP*65];
  int inst = blockIdx.x;
  size_t rowbase; unsigned short* dst; int h;
  if (inst < BB*HH){ int b_=inst/HH; h=inst%HH; rowbase=(size_t)b_*SS; dst = vT + (size_t)inst*HD*SP; }
  else { int i2=inst-BB*HH; int bm=i2/HH; h=i2%HH; rowbase=(size_t)BT+(size_t)bm*SS; dst = tvT + (size_t)i2*HD*SP; }
  int coff = 2*DD + h*HD;
  for (int i=threadIdx.x; i<SP*HD; i+=256){
    int k = i>>6, d = i&63;
    unsigned short v = (k<SS) ? qkv[(rowbase+k)*QLD + coff + d] : (unsigned short)0;
    tile[k*65+d] = v;
  }
  __syncthreads();
  for (int i=threadIdx.x; i<HD*SP; i+=256){
    int d = i/SP, k = i%SP;
    dst[(size_t)d*SP + k] = tile[k*65+d];
  }
}

// fused primal: scores + softmax -> abf & LDS, then PV -> obf. grid (4, BB*HH)
__global__ __launch_bounds__(256) void attn_s1_pv(const unsigned short* __restrict__ qkv,
    unsigned short* __restrict__ abf, const unsigned short* __restrict__ vT,
    unsigned short* __restrict__ obf){
  __shared__ __attribute__((aligned(16))) unsigned short pa[64*LDP];
  int qt = blockIdx.x, inst = blockIdx.y;      // inst = b*H+h
  int wave = threadIdx.x>>6, lane = threadIdx.x&63;
  int lrow = lane&15, lk = (lane>>4)<<3;
  int q0 = qt*64 + wave*16;
  f32x4 acc[13];
  f32x4 zf = {0.f,0.f,0.f,0.f};
  #pragma unroll
  for (int n=0;n<13;n++) acc[n]=zf;
  int h = inst % HH, b_ = inst / HH;
  size_t prow = (size_t)b_*SS;
  const unsigned short* Ab = qkv + (prow + q0 + lrow)*QLD + h*HD + lk;
  const unsigned short* Bb = qkv + prow*QLD + DD + h*HD + lk;
  #pragma unroll
  for (int kk=0; kk<HD; kk+=32){
    bf16x8 av = *(const bf16x8*)(Ab + kk);
    #pragma unroll
    for (int n=0;n<13;n++){
      bf16x8 bv = *(const bf16x8*)(Bb + (size_t)(n*16+lrow)*QLD + kk);
      acc[n] = mfma16(av, bv, acc[n]);
    }
  }
  int grp = lane>>4;
  unsigned short* obase = abf + (size_t)inst*SP*SP;
  bool okc12 = (lrow < 5);   // col 192+lrow < 197
  #pragma unroll
  for (int i=0;i<4;i++){
    int qr = q0 + grp*4 + i;
    float val[13], e[13];
    float mv = -1e30f;
    #pragma unroll
    for (int n=0;n<13;n++){
      val[n] = acc[n][i]*SCALE;
      if (n<12 || okc12) mv = fmaxf(mv, val[n]);
    }
    #pragma unroll
    for (int off=8; off; off>>=1) mv = fmaxf(mv, __shfl_xor(mv, off, 64));
    float s = 0.f;
    #pragma unroll
    for (int n=0;n<13;n++){
      e[n] = (n<12 || okc12) ? __expf(val[n]-mv) : 0.f;
      s += e[n];
    }
    #pragma unroll
    for (int off=8; off; off>>=1) s += __shfl_xor(s, off, 64);
    float inv = 1.f/s;
    unsigned short* lrp = pa + (size_t)(wave*16 + grp*4 + i)*LDP;
    unsigned short* orow = obase + (size_t)qr*SP;
    #pragma unroll
    for (int n=0;n<13;n++){
      unsigned short pv_ = f2bf(e[n]*inv);
      lrp[n*16+lrow] = pv_;
      if (qr < SS) orow[n*16+lrow] = pv_;
    }
  }
  __syncthreads();
  // ---- PV: o = a v ----
  f32x4 pacc[4];
  #pragma unroll
  for (int n=0;n<4;n++) pacc[n]=zf;
  const unsigned short* Vb = vT + (size_t)inst*HD*SP;
  const unsigned short* Arow = pa + (size_t)(wave*16 + lrow)*LDP;
  #pragma unroll
  for (int ks=0; ks<6; ks++){
    int kb = ks*32 + lk;
    bf16x8 av = *(const bf16x8*)(Arow + kb);
    #pragma unroll
    for (int n=0;n<4;n++){
      bf16x8 bv = *(const bf16x8*)(Vb + (size_t)(n*16+lrow)*SP + kb);
      pacc[n] = mfma16(av, bv, pacc[n]);
    }
  }
  {
    int kb = 192 + lk;
    const bf16x8 ZV = {0,0,0,0,0,0,0,0};
    bool ok = (lk < 16);
    bf16x8 av = ok ? *(const bf16x8*)(Arow + kb) : ZV;
    #pragma unroll
    for (int n=0;n<4;n++){
      bf16x8 bv = ok ? *(const bf16x8*)(Vb + (size_t)(n*16+lrow)*SP + kb) : ZV;
      pacc[n] = mfma16(av, bv, pacc[n]);
    }
  }
  size_t orow0 = (size_t)b_*SS;
  int qr0 = q0 + (grp<<2);
  #pragma unroll
  for (int n=0;n<4;n++){
    int cc = h*HD + n*16 + lrow;
    #pragma unroll
    for (int i=0;i<4;i++){
      int qr = qr0 + i;
      if (qr < SS) obf[(orow0+qr)*DD + cc] = f2bf(pacc[n][i]);
    }
  }
}

// fused tangent: ts + ta (LDS) + PV(ta v + a tv) -> obf. grid (4, BB*MM*HH)
__global__ __launch_bounds__(256) void attn_s2_pv(const unsigned short* __restrict__ qkv,
    const unsigned short* __restrict__ abf, const unsigned short* __restrict__ vT,
    const unsigned short* __restrict__ tvT, unsigned short* __restrict__ obf){
  __shared__ __attribute__((aligned(16))) unsigned short sa[64*LDP];  // primal probs tile
  __shared__ __attribute__((aligned(16))) unsigned short ta[64*LDP];  // tangent probs tile
  int qt = blockIdx.x, il = blockIdx.y;        // il = bmix*HH + h
  int wave = threadIdx.x>>6, lane = threadIdx.x&63;
  int lrow = lane&15, lk = (lane>>4)<<3;
  int q0 = qt*64 + wave*16;
  int h = il % HH;
  int bmix = il / HH;
  int b_ = bmix / MM;
  int bh = b_*HH + h;
  // cooperative stage of the primal-prob tile (rows qt*64 .. +64, clamped)
  {
    const unsigned short* abase = abf + (size_t)bh*SP*SP;
    int qb = qt*64;
    for (int c = threadIdx.x; c < 64*26; c += 256){
      int rl = c/26, c8 = (c%26)*8;
      int qr = qb + rl; if (qr > SS-1) qr = SS-1;
      *(bf16x8*)(sa + (size_t)rl*LDP + c8) = *(const bf16x8*)(abase + (size_t)qr*SP + c8);
    }
  }
  // ts = (tq k^T + q tk^T) * SCALE
  f32x4 acc[13];
  f32x4 zf = {0.f,0.f,0.f,0.f};
  #pragma unroll
  for (int n=0;n<13;n++) acc[n]=zf;
  size_t prow = (size_t)b_*SS;
  size_t trow = (size_t)BT + (size_t)bmix*SS;
  #pragma unroll
  for (int p=0;p<2;p++){
    size_t ar = (p==0) ? trow : prow;   // tq then q
    size_t br = (p==1) ? trow : prow;   // k  then tk
    const unsigned short* Ab = qkv + (ar + q0 + lrow)*QLD + h*HD + lk;
    const unsigned short* Bb = qkv + br*QLD + DD + h*HD + lk;
    #pragma unroll
    for (int kk=0; kk<HD; kk+=32){
      bf16x8 av = *(const bf16x8*)(Ab + kk);
      #pragma unroll
      for (int n=0;n<13;n++){
        bf16x8 bv = *(const bf16x8*)(Bb + (size_t)(n*16+lrow)*QLD + kk);
        acc[n] = mfma16(av, bv, acc[n]);
      }
    }
  }
  __syncthreads();          // sa staged; ts done
  int grp = lane>>4;
  #pragma unroll
  for (int i=0;i<4;i++){
    int rl = wave*16 + grp*4 + i;       // local q row
    const unsigned short* arow = sa + (size_t)rl*LDP;
    float av[13], tv[13];
    float dot = 0.f;
    #pragma unroll
    for (int n=0;n<13;n++){
      tv[n] = acc[n][i]*SCALE;
      av[n] = bf2f(arow[n*16+lrow]);
      dot += av[n]*tv[n];
    }
    #pragma unroll
    for (int off=8; off; off>>=1) dot += __shfl_xor(dot, off, 64);
    unsigned short* trp = ta + (size_t)rl*LDP;
    #pragma unroll
    for (int n=0;n<13;n++) trp[n*16+lrow] = f2bf(av[n]*(tv[n]-dot));
  }
  __syncthreads();          // ta ready
  // ---- PV: to = ta v + a tv ----
  f32x4 pacc[4];
  #pragma unroll
  for (int n=0;n<4;n++) pacc[n]=zf;
  #pragma unroll
  for (int p=0;p<2;p++){
    const unsigned short* Arow = (p==0 ? ta : sa) + (size_t)(wave*16 + lrow)*LDP;
    const unsigned short* Bb = (p==0) ? vT + (size_t)bh*HD*SP
                                      : tvT + (size_t)il*HD*SP;
    #pragma unroll
    for (int ks=0; ks<6; ks++){
      int kb = ks*32 + lk;
      bf16x8 av = *(const bf16x8*)(Arow + kb);
      #pragma unroll
      for (int n=0;n<4;n++){
        bf16x8 bv = *(const bf16x8*)(Bb + (size_t)(n*16+lrow)*SP + kb);
        pacc[n] = mfma16(av, bv, pacc[n]);
      }
    }
    {
      int kb = 192 + lk;
      const bf16x8 ZV = {0,0,0,0,0,0,0,0};
      bool ok = (lk < 16);
      bf16x8 av = ok ? *(const bf16x8*)(Arow + kb) : ZV;
      #pragma unroll
      for (int n=0;n<4;n++){
        bf16x8 bv = ok ? *(const bf16x8*)(Bb + (size_t)(n*16+lrow)*SP + kb) : ZV;
        pacc[n] = mfma16(av, bv, pacc[n]);
      }
    }
  }
  size_t orow0 = (size_t)BT + (size_t)bmix*SS;
  int qr0 = q0 + (grp<<2);
  #pragma unroll
  for (int n=0;n<4;n++){
    int cc = h*HD + n*16 + lrow;
    #pragma unroll
    for (int i=0;i<4;i++){
      int qr = qr0 + i;
      if (qr < SS) obf[(orow0+qr)*DD + cc] = f2bf(pacc[n][i]);
    }
  }
}

// ---------------- GELU JVP (grouped: primal + 4 tangents per block) ----------------
// grid BT: primal row -> pgbf; 4 tangent rows updated in place (share cdf/pdf)
__global__ __launch_bounds__(256) void gelu_group(unsigned short* __restrict__ fc1o,
                                                  unsigned short* __restrict__ pgbf){
  int r = blockIdx.x;
  int b_ = r/SS, s_ = r%SS;
  const bf16x8* pb = (const bf16x8*)(fc1o + (size_t)r*DFF);
  bf16x8* pg = (bf16x8*)(pgbf + (size_t)r*DFF);
  bf16x8* tb[4];
  #pragma unroll
  for (int m=0;m<4;m++)
    tb[m] = (bf16x8*)(fc1o + ((size_t)BT + (size_t)(b_*MM+m)*SS + s_)*DFF);
  for (int c = threadIdx.x; c < DFF/8; c += 256){
    bf16x8 xv = pb[c];
    float deriv[8];
    bf16x8 o;
    #pragma unroll
    for (int j=0;j<8;j++){
      float x = bf2f((unsigned short)xv[j]);
      float cdf = 0.5f*(1.f + erff(x*0.70710678118654752f));
      float pdf = __expf(-0.5f*x*x)*0.39894228040143267f;
      o[j] = (short)f2bf(x*cdf);
      deriv[j] = cdf + x*pdf;
    }
    pg[c] = o;
    #pragma unroll
    for (int m=0;m<4;m++){
      bf16x8 tv8 = tb[m][c];
      bf16x8 w;
      #pragma unroll
      for (int j=0;j<8;j++) w[j] = (short)f2bf(bf2f((unsigned short)tv8[j])*deriv[j]);
      tb[m][c] = w;
    }
  }
}

// ---------------- head ----------------
__global__ __launch_bounds__(256) void head_k(const unsigned short* __restrict__ ybf,
    const float* __restrict__ hw, const float* __restrict__ hb, float* __restrict__ out){
  __shared__ float ysh[DD];
  int ri = blockIdx.x;
  size_t yrow; float* o; bool wb;
  if (ri < BB){ yrow = (size_t)ri*SS; o = out + (size_t)ri*NCLS; wb = true; }
  else { int t2 = ri-BB; yrow = (size_t)BT + (size_t)t2*SS; o = out + (size_t)BB*NCLS + (size_t)t2*NCLS; wb = false; }
  for (int d=threadIdx.x; d<DD; d+=256) ysh[d] = bf2f(ybf[yrow*DD + d]);
  __syncthreads();
  for (int n=threadIdx.x; n<NCLS; n+=256){
    const float* wrow = hw + (size_t)n*DD;
    float acc = wb ? hb[n] : 0.f;
    for (int d=0; d<DD; d++) acc += ysh[d]*wrow[d];
    o[n] = acc;
  }
}

// ---------------- launch ----------------
extern "C" void kernel_launch(void* const* d_in, const int* in_sizes, int n_in,
                              void* d_out, int out_size, void* d_ws, size_t ws_size,
                              hipStream_t stream)
{
  const float* x      = (const float*)d_in[0];
  const float* xt     = (const float*)d_in[1];
  const float* patch_w= (const float*)d_in[2];
  const float* patch_b= (const float*)d_in[3];
  const float* cls    = (const float*)d_in[4];
  const float* pos    = (const float*)d_in[5];
  const float* ln1_g  = (const float*)d_in[6];
  const float* ln1_b  = (const float*)d_in[7];
  const float* qkv_w  = (const float*)d_in[8];
  const float* qkv_b  = (const float*)d_in[9];
  const float* proj_w = (const float*)d_in[10];
  const float* proj_b = (const float*)d_in[11];
  const float* ln2_g  = (const float*)d_in[12];
  const float* ln2_b  = (const float*)d_in[13];
  const float* fc1_w  = (const float*)d_in[14];
  const float* fc1_b  = (const float*)d_in[15];
  const float* fc2_w  = (const float*)d_in[16];
  const float* fc2_b  = (const float*)d_in[17];
  const float* nf_g   = (const float*)d_in[18];
  const float* nf_b   = (const float*)d_in[19];
  const float* head_w = (const float*)d_in[20];
  const float* head_b = (const float*)d_in[21];
  float* out = (float*)d_out;

  char* ws = (char*)d_ws;
  size_t off = 0;
  auto alloc = [&](size_t bytes)->char*{
    char* p = ws + off;
    off = (off + bytes + 255) & ~(size_t)255;
    return p;
  };

  unsigned short *w_patch, *wl, *ybf, *qkvbf, *vT, *tvT, *abf, *fc1o, *pgbf;
  float *hh;
  auto layout = [&](bool allw)->size_t{
    off = 0;
    w_patch = (unsigned short*)alloc((size_t)DD*DD*2);
    wl      = (unsigned short*)alloc((size_t)WTOT*2*(allw?LL:1));
    hh      = (float*)alloc((size_t)RP*DD*4);
    ybf     = (unsigned short*)alloc((size_t)RP*DD*2);
    size_t slab0 = off;
    qkvbf = (unsigned short*)alloc((size_t)RP*QLD*2);
    vT    = (unsigned short*)alloc((size_t)BB*HH*HD*SP*2);
    tvT   = (unsigned short*)alloc((size_t)BB*MM*HH*HD*SP*2);
    abf   = (unsigned short*)alloc((size_t)BB*HH*SP*SP*2);
    size_t endA = off;
    off = slab0;
    fc1o = (unsigned short*)alloc((size_t)RP*DFF*2);
    pgbf = (unsigned short*)alloc((size_t)BT*DFF*2);
    size_t endB = off;
    return (endA > endB) ? endA : endB;
  };

  bool allw = true;
  size_t need = layout(true);
  if (need > ws_size){ need = layout(false); allw = false; }
  if (need > ws_size){
    (void)hipMemsetAsync(d_out, 0x7f, (size_t)out_size*4, stream);   // loud sentinel
    return;
  }

  dim3 blk(256);
  f2bf8_kernel<<<dim3((DD*DD/8+255)/256), blk, 0, stream>>>(patch_w, w_patch, (size_t)DD*DD/8);
  if (allw)
    conv_all_v<<<dim3(WTOT/8/256, LL), blk, 0, stream>>>(qkv_w, proj_w, fc1_w, fc2_w, wl);
  init_h<<<dim3((RP*DD)/256), blk, 0, stream>>>(hh, cls, pos, patch_b);
  patchify_k<<<dim3((PRT*DD)/256), blk, 0, stream>>>(x, xt, ybf);
  gemm_bt<2><<<dim3(DD/128, 123), blk, 0, stream>>>(ybf, nullptr, 0, DD, w_patch, DD, DD, PRT,
                                                    hh, nullptr, DD, nullptr, 0);

  for (int l=0; l<LL; l++){
    if (!allw)
      conv_layer_v<<<dim3(WTOT/8/256), blk, 0, stream>>>(qkv_w+(size_t)l*NQW, proj_w+(size_t)l*NPW,
                                                         fc1_w+(size_t)l*NF1W, fc2_w+(size_t)l*NF2W, wl);
    const unsigned short* w_qkv = wl + (allw ? (size_t)l*WTOT : 0);
    const unsigned short* w_proj= w_qkv + NQW;
    const unsigned short* w_fc1 = w_qkv + NQW + NPW;
    const unsigned short* w_fc2 = w_qkv + NQW + NPW + NF1W;

    ln_group<<<dim3(BT), blk, 0, stream>>>(hh, ln1_g+(size_t)l*DD, ln1_b+(size_t)l*DD, ybf);
    gemm_bt<0><<<dim3(QLD/128, RP/128), blk, 0, stream>>>(ybf, nullptr, 0, DD, w_qkv,
        DD, QLD, RT, nullptr, qkvbf, QLD, qkv_b+(size_t)l*QLD, BT);
    transpose_v<<<dim3(BB*HH + BB*MM*HH), blk, 0, stream>>>(qkvbf, vT, tvT);
    attn_s1_pv<<<dim3(4, BB*HH), blk, 0, stream>>>(qkvbf, abf, vT, ybf);
    attn_s2_pv<<<dim3(4, BB*MM*HH), blk, 0, stream>>>(qkvbf, abf, vT, tvT, ybf);
    gemm_bt<1><<<dim3(DD/128, RP/128), blk, 0, stream>>>(ybf, nullptr, 0, DD, w_proj,
        DD, DD, RT, hh, nullptr, DD, proj_b+(size_t)l*DD, BT);
    ln_group<<<dim3(BT), blk, 0, stream>>>(hh, ln2_g+(size_t)l*DD, ln2_b+(size_t)l*DD, ybf);
    gemm_bt<0><<<dim3(DFF/128, RP/128), blk, 0, stream>>>(ybf, nullptr, 0, DD, w_fc1,
        DD, DFF, RT, nullptr, fc1o, DFF, fc1_b+(size_t)l*DFF, BT);
    gelu_group<<<dim3(BT), blk, 0, stream>>>(fc1o, pgbf);
    gemm_bt<1><<<dim3(DD/128, RP/128), blk, 0, stream>>>(fc1o, pgbf, BT, DFF, w_fc2,
        DFF, DD, RT, hh, nullptr, DD, fc2_b+(size_t)l*DD, BT);
  }

  ln_head<<<dim3(BB + BB*MM), blk, 0, stream>>>(hh, nf_g, nf_b, ybf);
  head_k<<<dim3(BB + BB*MM), blk, 0, stream>>>(ybf, head_w, head_b, out);
}